// Round 3
// baseline (231.031 us; speedup 1.0000x reference)
//
#include <hip/hip_runtime.h>

// Problem constants (from reference setup_inputs)
#define Bq 2
#define Cq 2
#define Dq 128
#define Hq 224
#define Wq 224
#define HWq (Hq * Wq)          // 50176
#define DHWq (Dq * HWq)        // 6422528
#define CDHWq (Cq * DHWq)      // 12845056
#define WT 32                  // w-tile width (224 = 7*32)
#define NWT (Wq / WT)          // 7

// Only z is displaced -> block (b,h,w-tile) with ALL z needs exactly
// src[b,:,:,h,w-tile]: no halo, each src element fetched once globally.
// Round 3: async global->LDS staging (no VGPR roundtrip) + flow prefetch
// into registers BEFORE the barrier, so both latency chains overlap.
__global__ __launch_bounds__(256) void st_zwarp_lds_kernel(
    const float* __restrict__ src, const float* __restrict__ flow,
    float* __restrict__ out)
{
    __shared__ float s[Cq * Dq * WT];   // 32 KB: s[c][z][w]

    const int tid = threadIdx.x;
    int blk = blockIdx.x;
    const int wt = blk % NWT;
    blk /= NWT;
    const int h = blk % Hq;
    const int b = blk / Hq;

    const float* src_b = src + b * CDHWq + h * Wq + wt * WT;

    // ---- async staging: 16 B/lane, LDS dest = wave-uniform base + lane*16.
    // Lane order == LDS order here (quad i4 lands at float offset i4*4).
    const int wv = tid >> 6;            // wave id 0..3
#pragma unroll
    for (int j = 0; j < (Cq * Dq * WT) / (256 * 4); ++j) {   // 8 iters
        const int i4 = j * 256 + tid;
        const int i  = i4 * 4;              // flat float index in tile
        const int c  = i >> 12;             // / (128*32)
        const int z  = (i >> 5) & (Dq - 1); // /32 % 128
        const int w  = i & (WT - 1);
        const float* g = src_b + c * DHWq + z * HWq + w;
        __builtin_amdgcn_global_load_lds(
            (const __attribute__((address_space(1))) unsigned int*)g,
            (__attribute__((address_space(3))) unsigned int*)(s + (j * 256 + wv * 64) * 4),
            16, 0, 0);
    }

    // ---- prefetch flow into registers (independent of LDS staging; these
    // loads fly concurrently with the staging DMA above).
    const int w  = tid & (WT - 1);
    const int zg = tid >> 5;                // 0..7, 16 z each
    const float* flow_b = flow + b * DHWq + h * Wq + wt * WT + w;
    float fl[16];
#pragma unroll
    for (int k = 0; k < 16; ++k) {
        fl[k] = flow_b[(zg * 16 + k) * HWq];
    }

    __syncthreads();   // drains staging DMA + flow loads together

    // ---- compute: pure LDS + FMA + coalesced stores, no global latency
    float* out_b = out + b * CDHWq + h * Wq + wt * WT + w;
#pragma unroll
    for (int k = 0; k < 16; ++k) {
        const int z = zg * 16 + k;
        float zc = fminf(fmaxf((float)z + fl[k], 0.0f), (float)(Dq - 1));
        const float zf = floorf(zc);
        const int z0 = (int)zf;
        const float wz = zc - zf;
        const int z1 = min(z0 + 1, Dq - 1);
#pragma unroll
        for (int c = 0; c < Cq; ++c) {
            const float s0 = s[c * (Dq * WT) + z0 * WT + w];
            const float s1 = s[c * (Dq * WT) + z1 * WT + w];
            out_b[c * DHWq + z * HWq] = s0 + (s1 - s0) * wz;
        }
    }
}

extern "C" void kernel_launch(void* const* d_in, const int* in_sizes, int n_in,
                              void* d_out, int out_size, void* d_ws, size_t ws_size,
                              hipStream_t stream) {
    const float* src  = (const float*)d_in[0];
    const float* flow = (const float*)d_in[1];
    float* out = (float*)d_out;

    const int grid = Bq * Hq * NWT;   // 3136
    st_zwarp_lds_kernel<<<grid, 256, 0, stream>>>(src, flow, out);
}